// Round 1
// baseline (196.542 us; speedup 1.0000x reference)
//
#include <hip/hip_runtime.h>
#include <hip/hip_bf16.h>
#include <math.h>

// Problem constants
#define DD  512
#define EE  8
#define FFD 2048
#define TT  2048
#define HWH 1024

typedef __bf16 b16x8 __attribute__((ext_vector_type(8)));
typedef float  f32x4 __attribute__((ext_vector_type(4)));

__device__ __forceinline__ unsigned short f2bf(float f) {
    unsigned u = __builtin_bit_cast(unsigned, f);
    u = (u + 0x7FFFu + ((u >> 16) & 1u)) >> 16;   // RNE
    return (unsigned short)u;
}

// ---------------- Router: logits/noise GEMV + noisy top-2 + gates ----------
__global__ void moe_router(const float* __restrict__ x,
                           const float* __restrict__ Wg, const float* __restrict__ bg,
                           const float* __restrict__ Wn, const float* __restrict__ bn,
                           const float* __restrict__ neps,
                           int* __restrict__ cnt, int* __restrict__ pair0, int* __restrict__ pair1,
                           int* __restrict__ ltok, float* __restrict__ lgate)
{
    int u = threadIdx.x & 63;   // token within block
    int q = threadIdx.x >> 6;   // d-quarter
    int t = blockIdx.x * 64 + u;
    int b = t >> 10, hw = t & 1023;
    const float* xp = x + (size_t)b * DD * HWH + hw;
    float accL[EE], accN[EE];
    #pragma unroll
    for (int e = 0; e < EE; ++e) { accL[e] = 0.f; accN[e] = 0.f; }
    for (int d = q * 128; d < q * 128 + 128; ++d) {
        float tv = xp[(size_t)d * HWH];
        #pragma unroll
        for (int e = 0; e < EE; ++e) {
            accL[e] = fmaf(tv, Wg[d * EE + e], accL[e]);
            accN[e] = fmaf(tv, Wn[d * EE + e], accN[e]);
        }
    }
    __shared__ float sL[4][64][EE];
    __shared__ float sN[4][64][EE];
    #pragma unroll
    for (int e = 0; e < EE; ++e) { sL[q][u][e] = accL[e]; sN[q][u][e] = accN[e]; }
    __syncthreads();
    if (q == 0) {
        float noisy[EE];
        #pragma unroll
        for (int e = 0; e < EE; ++e) {
            float L = sL[0][u][e] + sL[1][u][e] + sL[2][u][e] + sL[3][u][e] + bg[e];
            float R = sN[0][u][e] + sN[1][u][e] + sN[2][u][e] + sN[3][u][e] + bn[e];
            // jax.nn.softplus = logaddexp(x,0) = max(x,0) + log1p(exp(-|x|))
            float sp = fmaxf(R, 0.f) + log1pf(expf(-fabsf(R)));
            noisy[e] = L + neps[t * EE + e] * sp;
        }
        int e0 = 0; float v0 = noisy[0];
        #pragma unroll
        for (int e = 1; e < EE; ++e) if (noisy[e] > v0) { v0 = noisy[e]; e0 = e; }
        int e1 = (e0 == 0) ? 1 : 0; float v1 = noisy[e1];
        #pragma unroll
        for (int e = 0; e < EE; ++e)
            if (e != e0 && e != e1 && noisy[e] > v1) { v1 = noisy[e]; e1 = e; }
        float ex  = expf(v1 - v0);          // v1 <= v0, stable
        float inv = 1.f / (1.f + ex);
        float g0 = inv, g1 = ex * inv;      // softmax over the two kept logits
        int p0 = atomicAdd(&cnt[e0], 1);
        int p1 = atomicAdd(&cnt[e1], 1);
        ltok[e0 * TT + p0] = t; lgate[e0 * TT + p0] = g0;
        ltok[e1 * TT + p1] = t; lgate[e1 * TT + p1] = g1;
        pair0[t] = (e0 << 16) | p0;
        pair1[t] = (e1 << 16) | p1;
    }
}

// ---------------- Prefix sum over 8 expert counts --------------------------
__global__ void moe_prefix(const int* __restrict__ cnt, int* __restrict__ seg)
{
    if (threadIdx.x == 0) {
        int s = 0;
        for (int e = 0; e < EE; ++e) { seg[e] = s; s += cnt[e]; }
        seg[EE] = s;   // == 4096 always
    }
}

// ---------------- Gather selected tokens as bf16 rows ----------------------
__global__ void moe_gather(const float* __restrict__ x, const int* __restrict__ cnt,
                           const int* __restrict__ seg, const int* __restrict__ ltok,
                           unsigned short* __restrict__ Ag)
{
    int e = blockIdx.x, i = blockIdx.y;
    if (i >= cnt[e]) return;
    int t = ltok[e * TT + i];
    int b = t >> 10, hw = t & 1023;
    const float* xp = x + (size_t)b * DD * HWH + hw;
    unsigned short* ap = Ag + (size_t)(seg[e] + i) * DD;
    for (int d = threadIdx.x; d < DD; d += blockDim.x)
        ap[d] = f2bf(xp[(size_t)d * HWH]);
}

// ---------------- GEMM1: H = relu(A @ W1[e] + b1[e]) -----------------------
#define AST 40   // padded LDS row stride (bf16 units)
#define BST 40

__global__ __launch_bounds__(256, 2) void moe_gemm1(
    const unsigned short* __restrict__ Ag, const float* __restrict__ W1,
    const float* __restrict__ b1, const int* __restrict__ cnt,
    const int* __restrict__ seg, unsigned short* __restrict__ Hbuf)
{
    int e = blockIdx.x, mt = blockIdx.y, nt = blockIdx.z;
    int ce = cnt[e];
    if (mt * 64 >= ce) return;
    int s0 = seg[e];
    const float* W1e = W1 + (size_t)e * DD * FFD;
    __shared__ unsigned short As[64 * AST];
    __shared__ unsigned short Bs[256 * BST];
    int tid = threadIdx.x;
    int lane = tid & 63, wv = tid >> 6;
    f32x4 acc[4][4];
    f32x4 zero = {0.f, 0.f, 0.f, 0.f};
    #pragma unroll
    for (int m = 0; m < 4; ++m)
        #pragma unroll
        for (int n = 0; n < 4; ++n) acc[m][n] = zero;

    int arow = tid >> 2;            // 0..63
    int ako  = (tid & 3) * 8;       // 0,8,16,24
    int grow = s0 + mt * 64 + arow; if (grow > 4095) grow = 4095;
    const unsigned short* agp = Ag + (size_t)grow * DD + ako;
    int bc = tid;                   // 0..255  (B column within tile)
    int nb = nt * 256;
    int frow = lane & 15, fk = (lane >> 4) * 8;

    for (int kk = 0; kk < DD; kk += 32) {
        __syncthreads();
        // stage A tile [64 x 32] bf16 (one 16B vector per thread)
        *(b16x8*)(&As[arow * AST + ako]) = *(const b16x8*)(agp + kk);
        // stage B tile [32 x 256] fp32 -> bf16, transposed to [col][k]
        #pragma unroll
        for (int it = 0; it < 8; ++it) {
            int krow = it * 4;
            float v0 = W1e[(size_t)(kk + krow + 0) * FFD + nb + bc];
            float v1 = W1e[(size_t)(kk + krow + 1) * FFD + nb + bc];
            float v2 = W1e[(size_t)(kk + krow + 2) * FFD + nb + bc];
            float v3 = W1e[(size_t)(kk + krow + 3) * FFD + nb + bc];
            unsigned short* bp = &Bs[bc * BST + krow];
            bp[0] = f2bf(v0); bp[1] = f2bf(v1); bp[2] = f2bf(v2); bp[3] = f2bf(v3);
        }
        __syncthreads();
        b16x8 af[4], bfv[4];
        #pragma unroll
        for (int m = 0; m < 4; ++m)
            af[m] = *(const b16x8*)(&As[(m * 16 + frow) * AST + fk]);
        #pragma unroll
        for (int n = 0; n < 4; ++n)
            bfv[n] = *(const b16x8*)(&Bs[(wv * 64 + n * 16 + frow) * BST + fk]);
        #pragma unroll
        for (int m = 0; m < 4; ++m)
            #pragma unroll
            for (int n = 0; n < 4; ++n)
                acc[m][n] = __builtin_amdgcn_mfma_f32_16x16x32_bf16(af[m], bfv[n], acc[m][n], 0, 0, 0);
    }
    // epilogue: bias + relu -> H (bf16)
    int crow4 = (lane >> 4) * 4, ccol = lane & 15;
    #pragma unroll
    for (int m = 0; m < 4; ++m) {
        #pragma unroll
        for (int i = 0; i < 4; ++i) {
            int r = mt * 64 + m * 16 + crow4 + i;
            if (r < ce) {
                size_t prow = (size_t)(s0 + r);
                #pragma unroll
                for (int n = 0; n < 4; ++n) {
                    int c = nb + wv * 64 + n * 16 + ccol;
                    float v = acc[m][n][i] + b1[e * FFD + c];
                    v = fmaxf(v, 0.f);
                    Hbuf[prow * FFD + c] = f2bf(v);
                }
            }
        }
    }
}

// ---------------- GEMM2: P = gate * (H @ W2[e] + b2[e]) --------------------
__global__ __launch_bounds__(256, 2) void moe_gemm2(
    const unsigned short* __restrict__ Hbuf, const float* __restrict__ W2,
    const float* __restrict__ b2, const int* __restrict__ cnt,
    const int* __restrict__ seg, const float* __restrict__ lgate,
    float* __restrict__ P)
{
    int e = blockIdx.x, mt = blockIdx.y, nt = blockIdx.z;   // nt < 4
    int ce = cnt[e];
    if (mt * 64 >= ce) return;
    int s0 = seg[e];
    const float* W2e = W2 + (size_t)e * FFD * DD;
    __shared__ unsigned short As[64 * AST];
    __shared__ unsigned short Bs[128 * BST];
    int tid = threadIdx.x;
    int lane = tid & 63, wv = tid >> 6;
    f32x4 acc[4][2];
    f32x4 zero = {0.f, 0.f, 0.f, 0.f};
    #pragma unroll
    for (int m = 0; m < 4; ++m)
        #pragma unroll
        for (int n = 0; n < 2; ++n) acc[m][n] = zero;

    int arow = tid >> 2;
    int ako  = (tid & 3) * 8;
    int grow = s0 + mt * 64 + arow; if (grow > 4095) grow = 4095;
    const unsigned short* hp = Hbuf + (size_t)grow * FFD + ako;
    int bc  = tid & 127;            // col 0..127
    int bk0 = (tid >> 7) * 4;       // 0 or 4
    int nb = nt * 128;
    int frow = lane & 15, fk = (lane >> 4) * 8;

    for (int kk = 0; kk < FFD; kk += 32) {
        __syncthreads();
        *(b16x8*)(&As[arow * AST + ako]) = *(const b16x8*)(hp + kk);
        #pragma unroll
        for (int it = 0; it < 4; ++it) {
            int krow = bk0 + it * 8;
            float v0 = W2e[(size_t)(kk + krow + 0) * DD + nb + bc];
            float v1 = W2e[(size_t)(kk + krow + 1) * DD + nb + bc];
            float v2 = W2e[(size_t)(kk + krow + 2) * DD + nb + bc];
            float v3 = W2e[(size_t)(kk + krow + 3) * DD + nb + bc];
            unsigned short* bp = &Bs[bc * BST + krow];
            bp[0] = f2bf(v0); bp[1] = f2bf(v1); bp[2] = f2bf(v2); bp[3] = f2bf(v3);
        }
        __syncthreads();
        b16x8 af[4], bfv[2];
        #pragma unroll
        for (int m = 0; m < 4; ++m)
            af[m] = *(const b16x8*)(&As[(m * 16 + frow) * AST + fk]);
        #pragma unroll
        for (int n = 0; n < 2; ++n)
            bfv[n] = *(const b16x8*)(&Bs[(wv * 32 + n * 16 + frow) * BST + fk]);
        #pragma unroll
        for (int m = 0; m < 4; ++m)
            #pragma unroll
            for (int n = 0; n < 2; ++n)
                acc[m][n] = __builtin_amdgcn_mfma_f32_16x16x32_bf16(af[m], bfv[n], acc[m][n], 0, 0, 0);
    }
    int crow4 = (lane >> 4) * 4, ccol = lane & 15;
    #pragma unroll
    for (int m = 0; m < 4; ++m) {
        #pragma unroll
        for (int i = 0; i < 4; ++i) {
            int r = mt * 64 + m * 16 + crow4 + i;
            if (r < ce) {
                float g = lgate[e * TT + r];
                size_t prow = (size_t)(s0 + r);
                #pragma unroll
                for (int n = 0; n < 2; ++n) {
                    int c = nb + wv * 32 + n * 16 + ccol;
                    P[prow * DD + c] = g * (acc[m][n][i] + b2[e * DD + c]);
                }
            }
        }
    }
}

// ---------------- Combine: out[t,d] = P[p0,d] + P[p1,d] --------------------
__global__ void moe_combine(const int* __restrict__ pair0, const int* __restrict__ pair1,
                            const int* __restrict__ seg, const float* __restrict__ P,
                            float* __restrict__ out)
{
    int idx = blockIdx.x * 256 + threadIdx.x;     // 0 .. 2*512*1024-1
    int hw   = idx & 1023;
    int rest = idx >> 10;                          // b*512 + d
    int d = rest & 511;
    int b = rest >> 9;
    int t = b * 1024 + hw;
    int a0 = pair0[t], a1 = pair1[t];
    int p0 = seg[a0 >> 16] + (a0 & 0xFFFF);
    int p1 = seg[a1 >> 16] + (a1 & 0xFFFF);
    out[idx] = P[(size_t)p0 * DD + d] + P[(size_t)p1 * DD + d];
}

// ---------------- Launch ---------------------------------------------------
extern "C" void kernel_launch(void* const* d_in, const int* in_sizes, int n_in,
                              void* d_out, int out_size, void* d_ws, size_t ws_size,
                              hipStream_t stream)
{
    const float* x    = (const float*)d_in[0];
    const float* Wg   = (const float*)d_in[1];
    const float* bg   = (const float*)d_in[2];
    const float* Wn   = (const float*)d_in[3];
    const float* bn   = (const float*)d_in[4];
    const float* W1   = (const float*)d_in[5];
    const float* b1   = (const float*)d_in[6];
    const float* W2   = (const float*)d_in[7];
    const float* b2   = (const float*)d_in[8];
    const float* neps = (const float*)d_in[9];
    // d_in[10] = top_k (always 2)

    char* ws = (char*)d_ws;
    int*   cnt   = (int*)(ws + 0);                       // 8 ints
    int*   seg   = (int*)(ws + 256);                     // 9 ints
    int*   pair0 = (int*)(ws + 512);                     // T ints
    int*   pair1 = (int*)(ws + 512 + 8192);              // T ints
    int*   ltok  = (int*)(ws + 32768);                   // 8*T ints (64KB)
    float* lgate = (float*)(ws + 32768 + 65536);         // 8*T floats (64KB)
    unsigned short* Ag   = (unsigned short*)(ws + 262144);    // 4096*512 bf16 = 4MB
    unsigned short* Hbuf = (unsigned short*)(ws + 5242880);   // 4096*2048 bf16 = 16MB
    float*          P    = (float*)(ws + 23068672);           // 4096*512 f32 = 8MB
    // total ws usage ~30MB

    hipMemsetAsync(cnt, 0, 32, stream);
    moe_router<<<TT / 64, 256, 0, stream>>>(x, Wg, bg, Wn, bn, neps,
                                            cnt, pair0, pair1, ltok, lgate);
    moe_prefix<<<1, 64, 0, stream>>>(cnt, seg);
    moe_gather<<<dim3(EE, TT), 256, 0, stream>>>(x, cnt, seg, ltok, Ag);
    moe_gemm1<<<dim3(EE, 32, 8), 256, 0, stream>>>(Ag, W1, b1, cnt, seg, Hbuf);
    moe_gemm2<<<dim3(EE, 32, 4), 256, 0, stream>>>(Hbuf, W2, b2, cnt, seg, lgate, P);
    moe_combine<<<(2 * DD * HWH) / 256, 256, 0, stream>>>(pair0, pair1, seg, P, (float*)d_out);
}

// Round 2
// 129.952 us; speedup vs baseline: 1.5124x; 1.5124x over previous
//
#include <hip/hip_runtime.h>
#include <hip/hip_bf16.h>
#include <math.h>

// Problem constants
#define DD  512
#define EE  8
#define FFD 2048
#define TT  2048
#define HWH 1024

typedef __bf16 b16x8 __attribute__((ext_vector_type(8)));
typedef float  f32x4 __attribute__((ext_vector_type(4)));

__device__ __forceinline__ unsigned short f2bf(float f) {
    unsigned u = __builtin_bit_cast(unsigned, f);
    u = (u + 0x7FFFu + ((u >> 16) & 1u)) >> 16;   // RNE
    return (unsigned short)u;
}

// ---------- transpose/convert: f32 [R][C] -> bf16 [C][R] -------------------
// which=0: W1[e] 512x2048 -> W1t[e] 2048x512
// which=1: W2[e] 2048x512 -> W2t[e] 512x2048
// which=2: x[b]  512x1024 -> xb[b] 1024x512   (token-major bf16 activations)
__global__ __launch_bounds__(256) void moe_transpose(
    const float* __restrict__ W1, const float* __restrict__ W2,
    const float* __restrict__ x,
    unsigned short* __restrict__ W1t, unsigned short* __restrict__ W2t,
    unsigned short* __restrict__ xb)
{
    int which = blockIdx.z, e = blockIdx.y;
    const float* in; unsigned short* out; int R, C;
    if (which == 0)      { R = DD;  C = FFD; in = W1 + (size_t)e*DD*FFD; out = W1t + (size_t)e*FFD*DD; }
    else if (which == 1) { R = FFD; C = DD;  in = W2 + (size_t)e*FFD*DD; out = W2t + (size_t)e*DD*FFD; }
    else { if (e >= 2) return; R = DD; C = HWH; in = x + (size_t)e*DD*HWH; out = xb + (size_t)e*HWH*DD; }
    int tilesC = C >> 6;
    if ((int)blockIdx.x >= (R >> 6) * tilesC) return;
    int tr = (blockIdx.x / tilesC) << 6, tc = (blockIdx.x % tilesC) << 6;
    __shared__ float ld[64][65];
    int ty = threadIdx.x >> 4, tx = threadIdx.x & 15;
    #pragma unroll
    for (int i = 0; i < 4; ++i) {
        const float4 v = *(const float4*)&in[(size_t)(tr + ty + i*16)*C + tc + tx*4];
        ld[ty + i*16][tx*4+0] = v.x; ld[ty + i*16][tx*4+1] = v.y;
        ld[ty + i*16][tx*4+2] = v.z; ld[ty + i*16][tx*4+3] = v.w;
    }
    __syncthreads();
    #pragma unroll
    for (int i = 0; i < 4; ++i) {
        int c = ty + i*16;
        unsigned o0 = f2bf(ld[tx*4+0][c]) | ((unsigned)f2bf(ld[tx*4+1][c]) << 16);
        unsigned o1 = f2bf(ld[tx*4+2][c]) | ((unsigned)f2bf(ld[tx*4+3][c]) << 16);
        *(uint2*)&out[(size_t)(tc + c)*R + tr + tx*4] = make_uint2(o0, o1);
    }
}

// ---------------- Router: logits/noise GEMV + noisy top-2 + gates ----------
__global__ void moe_router(const float* __restrict__ x,
                           const float* __restrict__ Wg, const float* __restrict__ bg,
                           const float* __restrict__ Wn, const float* __restrict__ bn,
                           const float* __restrict__ neps,
                           int* __restrict__ cnt, int* __restrict__ pair0, int* __restrict__ pair1,
                           int* __restrict__ ltok, float* __restrict__ lgate)
{
    int u = threadIdx.x & 63;   // token within block
    int q = threadIdx.x >> 6;   // d-quarter
    int t = blockIdx.x * 64 + u;
    int b = t >> 10, hw = t & 1023;
    const float* xp = x + (size_t)b * DD * HWH + hw;
    float accL[EE], accN[EE];
    #pragma unroll
    for (int e = 0; e < EE; ++e) { accL[e] = 0.f; accN[e] = 0.f; }
    for (int d = q * 128; d < q * 128 + 128; ++d) {
        float tv = xp[(size_t)d * HWH];
        #pragma unroll
        for (int e = 0; e < EE; ++e) {
            accL[e] = fmaf(tv, Wg[d * EE + e], accL[e]);
            accN[e] = fmaf(tv, Wn[d * EE + e], accN[e]);
        }
    }
    __shared__ float sL[4][64][EE];
    __shared__ float sN[4][64][EE];
    #pragma unroll
    for (int e = 0; e < EE; ++e) { sL[q][u][e] = accL[e]; sN[q][u][e] = accN[e]; }
    __syncthreads();
    if (q == 0) {
        float noisy[EE];
        #pragma unroll
        for (int e = 0; e < EE; ++e) {
            float L = sL[0][u][e] + sL[1][u][e] + sL[2][u][e] + sL[3][u][e] + bg[e];
            float R = sN[0][u][e] + sN[1][u][e] + sN[2][u][e] + sN[3][u][e] + bn[e];
            float sp = fmaxf(R, 0.f) + log1pf(expf(-fabsf(R)));   // softplus
            noisy[e] = L + neps[t * EE + e] * sp;
        }
        int e0 = 0; float v0 = noisy[0];
        #pragma unroll
        for (int e = 1; e < EE; ++e) if (noisy[e] > v0) { v0 = noisy[e]; e0 = e; }
        int e1 = (e0 == 0) ? 1 : 0; float v1 = noisy[e1];
        #pragma unroll
        for (int e = 0; e < EE; ++e)
            if (e != e0 && e != e1 && noisy[e] > v1) { v1 = noisy[e]; e1 = e; }
        float ex  = expf(v1 - v0);
        float inv = 1.f / (1.f + ex);
        float g0 = inv, g1 = ex * inv;
        int p0 = atomicAdd(&cnt[e0], 1);
        int p1 = atomicAdd(&cnt[e1], 1);
        ltok[e0 * TT + p0] = t; lgate[e0 * TT + p0] = g0;
        ltok[e1 * TT + p1] = t; lgate[e1 * TT + p1] = g1;
        pair0[t] = (e0 << 16) | p0;
        pair1[t] = (e1 << 16) | p1;
    }
}

// ---------------- Prefix sum over 8 expert counts --------------------------
__global__ void moe_prefix(const int* __restrict__ cnt, int* __restrict__ seg)
{
    if (threadIdx.x == 0) {
        int s = 0;
        for (int e = 0; e < EE; ++e) { seg[e] = s; s += cnt[e]; }
        seg[EE] = s;
    }
}

// ---------------- GEMM1: H = relu(tok @ W1t^T + b1)  (64x128 tile, BK=64) --
__global__ __launch_bounds__(256, 3) void moe_gemm1(
    const unsigned short* __restrict__ xb, const unsigned short* __restrict__ W1t,
    const float* __restrict__ b1, const int* __restrict__ cnt,
    const int* __restrict__ seg, const int* __restrict__ ltok,
    unsigned short* __restrict__ Hbuf)
{
    int e = blockIdx.x, mt = blockIdx.y, nt = blockIdx.z;
    int ce = cnt[e];
    if (mt * 64 >= ce) return;
    int s0 = seg[e];
    const unsigned short* Be = W1t + (size_t)e * FFD * DD;   // [FF][D] bf16
    __shared__ unsigned short As[2][64 * 64];
    __shared__ unsigned short Bs[2][128 * 64];
    int tid = threadIdx.x, lane = tid & 63, wv = tid >> 6;

    // staging geometry: each 16B chunk -> (row = (call*4+wv)*8 + srow, chunk)
    int srow = lane >> 3, schunk = lane & 7;
    int sk = schunk * 8;                       // global k elems
    int swc = (schunk ^ srow) * 8;             // swizzled LDS chunk (elems)

    int tokA[2]; int awr[2];
    #pragma unroll
    for (int c = 0; c < 2; ++c) {
        int r = (c*4 + wv)*8 + srow;
        int ri = mt*64 + r;
        tokA[c] = ltok[e * TT + (ri < ce ? ri : 0)];
        awr[c] = r * 64 + swc;
    }
    int brow[4]; int bwr[4];
    #pragma unroll
    for (int c = 0; c < 4; ++c) {
        int r = (c*4 + wv)*8 + srow;
        brow[c] = nt*128 + r;
        bwr[c] = r * 64 + swc;
    }

    int frow = lane & 15, fk = (lane >> 4) * 8;
    int am = (wv >> 1) * 32, bn = (wv & 1) * 64;
    int rx = (frow & 7) << 3;                  // read-side xor (elems)

    f32x4 acc[2][4];
    f32x4 zero = {0.f, 0.f, 0.f, 0.f};
    #pragma unroll
    for (int m = 0; m < 2; ++m)
        #pragma unroll
        for (int n = 0; n < 4; ++n) acc[m][n] = zero;

    b16x8 ra[2], rb[4];
    // prologue: stage k-tile 0 into buf 0
    #pragma unroll
    for (int c = 0; c < 2; ++c) ra[c] = *(const b16x8*)&xb[(size_t)tokA[c]*DD + sk];
    #pragma unroll
    for (int c = 0; c < 4; ++c) rb[c] = *(const b16x8*)&Be[(size_t)brow[c]*DD + sk];
    #pragma unroll
    for (int c = 0; c < 2; ++c) *(b16x8*)&As[0][awr[c]] = ra[c];
    #pragma unroll
    for (int c = 0; c < 4; ++c) *(b16x8*)&Bs[0][bwr[c]] = rb[c];
    __syncthreads();

    int cur = 0;
    for (int t = 0; t < 8; ++t) {
        if (t < 7) {
            int kk = (t + 1) * 64;
            #pragma unroll
            for (int c = 0; c < 2; ++c) ra[c] = *(const b16x8*)&xb[(size_t)tokA[c]*DD + kk + sk];
            #pragma unroll
            for (int c = 0; c < 4; ++c) rb[c] = *(const b16x8*)&Be[(size_t)brow[c]*DD + kk + sk];
        }
        #pragma unroll
        for (int k2 = 0; k2 < 64; k2 += 32) {
            b16x8 af[2], bf[4];
            #pragma unroll
            for (int m = 0; m < 2; ++m)
                af[m] = *(const b16x8*)&As[cur][(am + m*16 + frow)*64 + ((k2 + fk) ^ rx)];
            #pragma unroll
            for (int n = 0; n < 4; ++n)
                bf[n] = *(const b16x8*)&Bs[cur][(bn + n*16 + frow)*64 + ((k2 + fk) ^ rx)];
            #pragma unroll
            for (int m = 0; m < 2; ++m)
                #pragma unroll
                for (int n = 0; n < 4; ++n)
                    acc[m][n] = __builtin_amdgcn_mfma_f32_16x16x32_bf16(af[m], bf[n], acc[m][n], 0, 0, 0);
        }
        __syncthreads();
        if (t < 7) {
            #pragma unroll
            for (int c = 0; c < 2; ++c) *(b16x8*)&As[cur ^ 1][awr[c]] = ra[c];
            #pragma unroll
            for (int c = 0; c < 4; ++c) *(b16x8*)&Bs[cur ^ 1][bwr[c]] = rb[c];
        }
        __syncthreads();
        cur ^= 1;
    }

    int crow = (lane >> 4) * 4;
    #pragma unroll
    for (int m = 0; m < 2; ++m) {
        #pragma unroll
        for (int i = 0; i < 4; ++i) {
            int r = mt*64 + am + m*16 + crow + i;
            if (r < ce) {
                size_t hrow = (size_t)(s0 + r) * FFD;
                #pragma unroll
                for (int n = 0; n < 4; ++n) {
                    int col = nt*128 + bn + n*16 + frow;
                    float v = acc[m][n][i] + b1[e * FFD + col];
                    Hbuf[hrow + col] = f2bf(fmaxf(v, 0.f));
                }
            }
        }
    }
}

// ---------------- GEMM2: P = gate * (H @ W2t^T + b2) (64x64 tile, BK=64) ---
__global__ __launch_bounds__(256, 4) void moe_gemm2(
    const unsigned short* __restrict__ Hbuf, const unsigned short* __restrict__ W2t,
    const float* __restrict__ b2, const int* __restrict__ cnt,
    const int* __restrict__ seg, const float* __restrict__ lgate,
    float* __restrict__ P)
{
    int e = blockIdx.x, mt = blockIdx.y, nt = blockIdx.z;
    int ce = cnt[e];
    if (mt * 64 >= ce) return;
    int s0 = seg[e];
    const unsigned short* Be = W2t + (size_t)e * DD * FFD;   // [D][FF] bf16
    __shared__ unsigned short As[2][64 * 64];
    __shared__ unsigned short Bs[2][64 * 64];
    int tid = threadIdx.x, lane = tid & 63, wv = tid >> 6;

    int srow = lane >> 3, schunk = lane & 7;
    int sk = schunk * 8;
    int swc = (schunk ^ srow) * 8;

    int agr[2]; int awr[2];
    #pragma unroll
    for (int c = 0; c < 2; ++c) {
        int r = (c*4 + wv)*8 + srow;
        int g = s0 + mt*64 + r; if (g > 4095) g = 4095;
        agr[c] = g;
        awr[c] = r * 64 + swc;
    }
    int brow[2]; int bwr[2];
    #pragma unroll
    for (int c = 0; c < 2; ++c) {
        int r = (c*4 + wv)*8 + srow;
        brow[c] = nt*64 + r;
        bwr[c] = r * 64 + swc;
    }

    int frow = lane & 15, fk = (lane >> 4) * 8;
    int am = (wv >> 1) * 32, bn = (wv & 1) * 32;
    int rx = (frow & 7) << 3;

    f32x4 acc[2][2];
    f32x4 zero = {0.f, 0.f, 0.f, 0.f};
    #pragma unroll
    for (int m = 0; m < 2; ++m)
        #pragma unroll
        for (int n = 0; n < 2; ++n) acc[m][n] = zero;

    b16x8 ra[2], rb[2];
    #pragma unroll
    for (int c = 0; c < 2; ++c) ra[c] = *(const b16x8*)&Hbuf[(size_t)agr[c]*FFD + sk];
    #pragma unroll
    for (int c = 0; c < 2; ++c) rb[c] = *(const b16x8*)&Be[(size_t)brow[c]*FFD + sk];
    #pragma unroll
    for (int c = 0; c < 2; ++c) *(b16x8*)&As[0][awr[c]] = ra[c];
    #pragma unroll
    for (int c = 0; c < 2; ++c) *(b16x8*)&Bs[0][bwr[c]] = rb[c];
    __syncthreads();

    int cur = 0;
    for (int t = 0; t < 32; ++t) {
        if (t < 31) {
            int kk = (t + 1) * 64;
            #pragma unroll
            for (int c = 0; c < 2; ++c) ra[c] = *(const b16x8*)&Hbuf[(size_t)agr[c]*FFD + kk + sk];
            #pragma unroll
            for (int c = 0; c < 2; ++c) rb[c] = *(const b16x8*)&Be[(size_t)brow[c]*FFD + kk + sk];
        }
        #pragma unroll
        for (int k2 = 0; k2 < 64; k2 += 32) {
            b16x8 af[2], bf[2];
            #pragma unroll
            for (int m = 0; m < 2; ++m)
                af[m] = *(const b16x8*)&As[cur][(am + m*16 + frow)*64 + ((k2 + fk) ^ rx)];
            #pragma unroll
            for (int n = 0; n < 2; ++n)
                bf[n] = *(const b16x8*)&Bs[cur][(bn + n*16 + frow)*64 + ((k2 + fk) ^ rx)];
            #pragma unroll
            for (int m = 0; m < 2; ++m)
                #pragma unroll
                for (int n = 0; n < 2; ++n)
                    acc[m][n] = __builtin_amdgcn_mfma_f32_16x16x32_bf16(af[m], bf[n], acc[m][n], 0, 0, 0);
        }
        __syncthreads();
        if (t < 31) {
            #pragma unroll
            for (int c = 0; c < 2; ++c) *(b16x8*)&As[cur ^ 1][awr[c]] = ra[c];
            #pragma unroll
            for (int c = 0; c < 2; ++c) *(b16x8*)&Bs[cur ^ 1][bwr[c]] = rb[c];
        }
        __syncthreads();
        cur ^= 1;
    }

    int crow = (lane >> 4) * 4;
    #pragma unroll
    for (int m = 0; m < 2; ++m) {
        #pragma unroll
        for (int i = 0; i < 4; ++i) {
            int r = mt*64 + am + m*16 + crow + i;
            if (r < ce) {
                float g = lgate[e * TT + r];
                size_t prow = (size_t)(s0 + r) * DD;
                #pragma unroll
                for (int n = 0; n < 2; ++n) {
                    int col = nt*64 + bn + n*16 + frow;
                    P[prow + col] = g * (acc[m][n][i] + b2[e * DD + col]);
                }
            }
        }
    }
}

// ---------------- Combine: out[t,d] = P[p0,d] + P[p1,d] --------------------
__global__ void moe_combine(const int* __restrict__ pair0, const int* __restrict__ pair1,
                            const int* __restrict__ seg, const float* __restrict__ P,
                            float* __restrict__ out)
{
    int idx = blockIdx.x * 256 + threadIdx.x;
    int hw   = idx & 1023;
    int rest = idx >> 10;
    int d = rest & 511;
    int b = rest >> 9;
    int t = b * 1024 + hw;
    int a0 = pair0[t], a1 = pair1[t];
    int p0 = seg[a0 >> 16] + (a0 & 0xFFFF);
    int p1 = seg[a1 >> 16] + (a1 & 0xFFFF);
    out[idx] = P[(size_t)p0 * DD + d] + P[(size_t)p1 * DD + d];
}

// ---------------- Launch ---------------------------------------------------
extern "C" void kernel_launch(void* const* d_in, const int* in_sizes, int n_in,
                              void* d_out, int out_size, void* d_ws, size_t ws_size,
                              hipStream_t stream)
{
    const float* x    = (const float*)d_in[0];
    const float* Wg   = (const float*)d_in[1];
    const float* bg   = (const float*)d_in[2];
    const float* Wn   = (const float*)d_in[3];
    const float* bn   = (const float*)d_in[4];
    const float* W1   = (const float*)d_in[5];
    const float* b1   = (const float*)d_in[6];
    const float* W2   = (const float*)d_in[7];
    const float* b2   = (const float*)d_in[8];
    const float* neps = (const float*)d_in[9];

    char* ws = (char*)d_ws;
    int*   cnt   = (int*)(ws + 0);                       // 32 B
    int*   seg   = (int*)(ws + 256);                     // 36 B
    int*   pair0 = (int*)(ws + 512);                     // 8 KB
    int*   pair1 = (int*)(ws + 8704);                    // 8 KB
    int*   ltok  = (int*)(ws + 32768);                   // 64 KB
    float* lgate = (float*)(ws + 98304);                 // 64 KB
    unsigned short* xb   = (unsigned short*)(ws + 262144);    // 2 MB  [2048][512] bf16
    unsigned short* Hbuf = (unsigned short*)(ws + 2359296);   // 16 MB [4096][2048] bf16
    unsigned short* W1t  = (unsigned short*)(ws + 19136512);  // 16 MB [E][2048][512] bf16
    unsigned short* W2t  = (unsigned short*)(ws + 35913728);  // 16 MB [E][512][2048] bf16
    float*          P    = (float*)(ws + 19136512);           // 8 MB, aliases W1t (dead after gemm1)

    hipMemsetAsync(cnt, 0, 32, stream);
    moe_transpose<<<dim3(256, 8, 3), 256, 0, stream>>>(W1, W2, x, W1t, W2t, xb);
    moe_router<<<TT / 64, 256, 0, stream>>>(x, Wg, bg, Wn, bn, neps,
                                            cnt, pair0, pair1, ltok, lgate);
    moe_prefix<<<1, 64, 0, stream>>>(cnt, seg);
    moe_gemm1<<<dim3(EE, 32, 16), 256, 0, stream>>>(xb, W1t, b1, cnt, seg, ltok, Hbuf);
    moe_gemm2<<<dim3(EE, 32, 8), 256, 0, stream>>>(Hbuf, W2t, b2, cnt, seg, lgate, P);
    moe_combine<<<(2 * DD * HWH) / 256, 256, 0, stream>>>(pair0, pair1, seg, P, (float*)d_out);
}

// Round 3
// 124.699 us; speedup vs baseline: 1.5761x; 1.0421x over previous
//
#include <hip/hip_runtime.h>
#include <hip/hip_bf16.h>
#include <math.h>

// Problem constants
#define DD  512
#define EE  8
#define FFD 2048
#define TT  2048
#define HWH 1024

typedef __bf16 b16x8 __attribute__((ext_vector_type(8)));
typedef float  f32x4 __attribute__((ext_vector_type(4)));

__device__ __forceinline__ unsigned short f2bf(float f) {
    unsigned u = __builtin_bit_cast(unsigned, f);
    u = (u + 0x7FFFu + ((u >> 16) & 1u)) >> 16;   // RNE
    return (unsigned short)u;
}

// ---------- transpose/convert: f32 [R][C] -> bf16 [C][R] -------------------
// which=0: W1[e] 512x2048 -> W1t[e] 2048x512
// which=1: W2[e] 2048x512 -> W2t[e] 512x2048
// which=2: x[b]  512x1024 -> xb[b] 1024x512   (token-major bf16 activations)
__global__ __launch_bounds__(256) void moe_transpose(
    const float* __restrict__ W1, const float* __restrict__ W2,
    const float* __restrict__ x,
    unsigned short* __restrict__ W1t, unsigned short* __restrict__ W2t,
    unsigned short* __restrict__ xb)
{
    int which = blockIdx.z, e = blockIdx.y;
    const float* in; unsigned short* out; int R, C;
    if (which == 0)      { R = DD;  C = FFD; in = W1 + (size_t)e*DD*FFD; out = W1t + (size_t)e*FFD*DD; }
    else if (which == 1) { R = FFD; C = DD;  in = W2 + (size_t)e*FFD*DD; out = W2t + (size_t)e*DD*FFD; }
    else { if (e >= 2) return; R = DD; C = HWH; in = x + (size_t)e*DD*HWH; out = xb + (size_t)e*HWH*DD; }
    int tilesC = C >> 6;
    if ((int)blockIdx.x >= (R >> 6) * tilesC) return;
    int tr = (blockIdx.x / tilesC) << 6, tc = (blockIdx.x % tilesC) << 6;
    __shared__ float ld[64][65];
    int ty = threadIdx.x >> 4, tx = threadIdx.x & 15;
    #pragma unroll
    for (int i = 0; i < 4; ++i) {
        const float4 v = *(const float4*)&in[(size_t)(tr + ty + i*16)*C + tc + tx*4];
        ld[ty + i*16][tx*4+0] = v.x; ld[ty + i*16][tx*4+1] = v.y;
        ld[ty + i*16][tx*4+2] = v.z; ld[ty + i*16][tx*4+3] = v.w;
    }
    __syncthreads();
    #pragma unroll
    for (int i = 0; i < 4; ++i) {
        int c = ty + i*16;
        unsigned o0 = f2bf(ld[tx*4+0][c]) | ((unsigned)f2bf(ld[tx*4+1][c]) << 16);
        unsigned o1 = f2bf(ld[tx*4+2][c]) | ((unsigned)f2bf(ld[tx*4+3][c]) << 16);
        *(uint2*)&out[(size_t)(tc + c)*R + tr + tx*4] = make_uint2(o0, o1);
    }
}

// ---------------- Router stage A: partial GEMV over a 64-d slice -----------
// part layout: [8 dchunk][2048 token][16 (L0..7,N0..7)] f32  (1 MB)
__global__ __launch_bounds__(256) void moe_router_part(
    const float* __restrict__ x, const float* __restrict__ Wg,
    const float* __restrict__ Wn, float* __restrict__ part)
{
    int u = threadIdx.x & 63;   // token within tile
    int q = threadIdx.x >> 6;   // 16-d sub-slice
    int tt = blockIdx.x, dc = blockIdx.y;
    int t = tt * 64 + u;
    int b = t >> 10, hw = t & 1023;
    const float* xp = x + (size_t)b * DD * HWH + hw;
    int d0 = dc * 64 + q * 16;
    float accL[EE], accN[EE];
    #pragma unroll
    for (int e = 0; e < EE; ++e) { accL[e] = 0.f; accN[e] = 0.f; }
    #pragma unroll
    for (int i = 0; i < 16; ++i) {
        int d = d0 + i;
        float tv = xp[(size_t)d * HWH];
        #pragma unroll
        for (int e = 0; e < EE; ++e) {
            accL[e] = fmaf(tv, Wg[d * EE + e], accL[e]);
            accN[e] = fmaf(tv, Wn[d * EE + e], accN[e]);
        }
    }
    __shared__ float s[4][64][16];
    #pragma unroll
    for (int e = 0; e < EE; ++e) { s[q][u][e] = accL[e]; s[q][u][e + 8] = accN[e]; }
    __syncthreads();
    // 1024 outputs, 256 threads -> one float4 each, coalesced
    int idx = threadIdx.x * 4;
    int ot = idx >> 4, oc = idx & 15;
    float4 v;
    v.x = s[0][ot][oc+0] + s[1][ot][oc+0] + s[2][ot][oc+0] + s[3][ot][oc+0];
    v.y = s[0][ot][oc+1] + s[1][ot][oc+1] + s[2][ot][oc+1] + s[3][ot][oc+1];
    v.z = s[0][ot][oc+2] + s[1][ot][oc+2] + s[2][ot][oc+2] + s[3][ot][oc+2];
    v.w = s[0][ot][oc+3] + s[1][ot][oc+3] + s[2][ot][oc+3] + s[3][ot][oc+3];
    *(float4*)&part[((size_t)dc * TT + tt * 64 + ot) * 16 + oc] = v;
}

// ---------------- Router stage B: reduce + noisy top-2 + gates -------------
__global__ __launch_bounds__(256) void moe_router_topk(
    const float* __restrict__ part,
    const float* __restrict__ bg, const float* __restrict__ bn,
    const float* __restrict__ neps,
    int* __restrict__ cnt, int* __restrict__ pair0, int* __restrict__ pair1,
    int* __restrict__ ltok, float* __restrict__ lgate)
{
    int t = blockIdx.x * 256 + threadIdx.x;
    float L[EE], N[EE];
    #pragma unroll
    for (int e = 0; e < EE; ++e) { L[e] = bg[e]; N[e] = bn[e]; }
    #pragma unroll
    for (int dc = 0; dc < 8; ++dc) {
        const float* p = &part[((size_t)dc * TT + t) * 16];
        float4 a0 = *(const float4*)&p[0];
        float4 a1 = *(const float4*)&p[4];
        float4 a2 = *(const float4*)&p[8];
        float4 a3 = *(const float4*)&p[12];
        L[0] += a0.x; L[1] += a0.y; L[2] += a0.z; L[3] += a0.w;
        L[4] += a1.x; L[5] += a1.y; L[6] += a1.z; L[7] += a1.w;
        N[0] += a2.x; N[1] += a2.y; N[2] += a2.z; N[3] += a2.w;
        N[4] += a3.x; N[5] += a3.y; N[6] += a3.z; N[7] += a3.w;
    }
    float noisy[EE];
    #pragma unroll
    for (int e = 0; e < EE; ++e) {
        float sp = fmaxf(N[e], 0.f) + log1pf(expf(-fabsf(N[e])));   // softplus
        noisy[e] = L[e] + neps[t * EE + e] * sp;
    }
    int e0 = 0; float v0 = noisy[0];
    #pragma unroll
    for (int e = 1; e < EE; ++e) if (noisy[e] > v0) { v0 = noisy[e]; e0 = e; }
    int e1 = (e0 == 0) ? 1 : 0; float v1 = noisy[e1];
    #pragma unroll
    for (int e = 0; e < EE; ++e)
        if (e != e0 && e != e1 && noisy[e] > v1) { v1 = noisy[e]; e1 = e; }
    float ex  = expf(v1 - v0);
    float inv = 1.f / (1.f + ex);
    float g0 = inv, g1 = ex * inv;
    int p0 = atomicAdd(&cnt[e0], 1);
    int p1 = atomicAdd(&cnt[e1], 1);
    ltok[e0 * TT + p0] = t; lgate[e0 * TT + p0] = g0;
    ltok[e1 * TT + p1] = t; lgate[e1 * TT + p1] = g1;
    pair0[t] = (e0 << 16) | p0;
    pair1[t] = (e1 << 16) | p1;
}

// ---------------- Prefix sum over 8 expert counts --------------------------
__global__ void moe_prefix(const int* __restrict__ cnt, int* __restrict__ seg)
{
    if (threadIdx.x == 0) {
        int s = 0;
        for (int e = 0; e < EE; ++e) { seg[e] = s; s += cnt[e]; }
        seg[EE] = s;
    }
}

// ---------------- GEMM1: H = relu(tok @ W1t^T + b1)  (64x128 tile, BK=64) --
__global__ __launch_bounds__(256, 3) void moe_gemm1(
    const unsigned short* __restrict__ xb, const unsigned short* __restrict__ W1t,
    const float* __restrict__ b1, const int* __restrict__ cnt,
    const int* __restrict__ seg, const int* __restrict__ ltok,
    unsigned short* __restrict__ Hbuf)
{
    int e = blockIdx.x, mt = blockIdx.y, nt = blockIdx.z;
    int ce = cnt[e];
    if (mt * 64 >= ce) return;
    int s0 = seg[e];
    const unsigned short* Be = W1t + (size_t)e * FFD * DD;   // [FF][D] bf16
    __shared__ unsigned short As[2][64 * 64];
    __shared__ unsigned short Bs[2][128 * 64];
    int tid = threadIdx.x, lane = tid & 63, wv = tid >> 6;

    int srow = lane >> 3, schunk = lane & 7;
    int sk = schunk * 8;
    int swc = (schunk ^ srow) * 8;

    int tokA[2]; int awr[2];
    #pragma unroll
    for (int c = 0; c < 2; ++c) {
        int r = (c*4 + wv)*8 + srow;
        int ri = mt*64 + r;
        tokA[c] = ltok[e * TT + (ri < ce ? ri : 0)];
        awr[c] = r * 64 + swc;
    }
    int brow[4]; int bwr[4];
    #pragma unroll
    for (int c = 0; c < 4; ++c) {
        int r = (c*4 + wv)*8 + srow;
        brow[c] = nt*128 + r;
        bwr[c] = r * 64 + swc;
    }

    int frow = lane & 15, fk = (lane >> 4) * 8;
    int am = (wv >> 1) * 32, bn = (wv & 1) * 64;
    int rx = (frow & 7) << 3;

    f32x4 acc[2][4];
    f32x4 zero = {0.f, 0.f, 0.f, 0.f};
    #pragma unroll
    for (int m = 0; m < 2; ++m)
        #pragma unroll
        for (int n = 0; n < 4; ++n) acc[m][n] = zero;

    b16x8 ra[2], rb[4];
    #pragma unroll
    for (int c = 0; c < 2; ++c) ra[c] = *(const b16x8*)&xb[(size_t)tokA[c]*DD + sk];
    #pragma unroll
    for (int c = 0; c < 4; ++c) rb[c] = *(const b16x8*)&Be[(size_t)brow[c]*DD + sk];
    #pragma unroll
    for (int c = 0; c < 2; ++c) *(b16x8*)&As[0][awr[c]] = ra[c];
    #pragma unroll
    for (int c = 0; c < 4; ++c) *(b16x8*)&Bs[0][bwr[c]] = rb[c];
    __syncthreads();

    int cur = 0;
    for (int t = 0; t < 8; ++t) {
        if (t < 7) {
            int kk = (t + 1) * 64;
            #pragma unroll
            for (int c = 0; c < 2; ++c) ra[c] = *(const b16x8*)&xb[(size_t)tokA[c]*DD + kk + sk];
            #pragma unroll
            for (int c = 0; c < 4; ++c) rb[c] = *(const b16x8*)&Be[(size_t)brow[c]*DD + kk + sk];
        }
        #pragma unroll
        for (int k2 = 0; k2 < 64; k2 += 32) {
            b16x8 af[2], bf[4];
            #pragma unroll
            for (int m = 0; m < 2; ++m)
                af[m] = *(const b16x8*)&As[cur][(am + m*16 + frow)*64 + ((k2 + fk) ^ rx)];
            #pragma unroll
            for (int n = 0; n < 4; ++n)
                bf[n] = *(const b16x8*)&Bs[cur][(bn + n*16 + frow)*64 + ((k2 + fk) ^ rx)];
            #pragma unroll
            for (int m = 0; m < 2; ++m)
                #pragma unroll
                for (int n = 0; n < 4; ++n)
                    acc[m][n] = __builtin_amdgcn_mfma_f32_16x16x32_bf16(af[m], bf[n], acc[m][n], 0, 0, 0);
        }
        __syncthreads();
        if (t < 7) {
            #pragma unroll
            for (int c = 0; c < 2; ++c) *(b16x8*)&As[cur ^ 1][awr[c]] = ra[c];
            #pragma unroll
            for (int c = 0; c < 4; ++c) *(b16x8*)&Bs[cur ^ 1][bwr[c]] = rb[c];
        }
        __syncthreads();
        cur ^= 1;
    }

    int crow = (lane >> 4) * 4;
    #pragma unroll
    for (int m = 0; m < 2; ++m) {
        #pragma unroll
        for (int i = 0; i < 4; ++i) {
            int r = mt*64 + am + m*16 + crow + i;
            if (r < ce) {
                size_t hrow = (size_t)(s0 + r) * FFD;
                #pragma unroll
                for (int n = 0; n < 4; ++n) {
                    int col = nt*128 + bn + n*16 + frow;
                    float v = acc[m][n][i] + b1[e * FFD + col];
                    Hbuf[hrow + col] = f2bf(fmaxf(v, 0.f));
                }
            }
        }
    }
}

// ---------------- GEMM2: P = gate * (H @ W2t^T + b2) (64x128 tile, BK=64) --
__global__ __launch_bounds__(256, 3) void moe_gemm2(
    const unsigned short* __restrict__ Hbuf, const unsigned short* __restrict__ W2t,
    const float* __restrict__ b2, const int* __restrict__ cnt,
    const int* __restrict__ seg, const float* __restrict__ lgate,
    float* __restrict__ P)
{
    int e = blockIdx.x, mt = blockIdx.y, nt = blockIdx.z;   // nt < 4
    int ce = cnt[e];
    if (mt * 64 >= ce) return;
    int s0 = seg[e];
    const unsigned short* Be = W2t + (size_t)e * DD * FFD;   // [D][FF] bf16
    __shared__ unsigned short As[2][64 * 64];
    __shared__ unsigned short Bs[2][128 * 64];
    int tid = threadIdx.x, lane = tid & 63, wv = tid >> 6;

    int srow = lane >> 3, schunk = lane & 7;
    int sk = schunk * 8;
    int swc = (schunk ^ srow) * 8;

    int agr[2]; int awr[2];
    #pragma unroll
    for (int c = 0; c < 2; ++c) {
        int r = (c*4 + wv)*8 + srow;
        int g = s0 + mt*64 + r; if (g > 4095) g = 4095;
        agr[c] = g;
        awr[c] = r * 64 + swc;
    }
    int brow[4]; int bwr[4];
    #pragma unroll
    for (int c = 0; c < 4; ++c) {
        int r = (c*4 + wv)*8 + srow;
        brow[c] = nt*128 + r;
        bwr[c] = r * 64 + swc;
    }

    int frow = lane & 15, fk = (lane >> 4) * 8;
    int am = (wv >> 1) * 32, bn = (wv & 1) * 64;
    int rx = (frow & 7) << 3;

    f32x4 acc[2][4];
    f32x4 zero = {0.f, 0.f, 0.f, 0.f};
    #pragma unroll
    for (int m = 0; m < 2; ++m)
        #pragma unroll
        for (int n = 0; n < 4; ++n) acc[m][n] = zero;

    b16x8 ra[2], rb[4];
    #pragma unroll
    for (int c = 0; c < 2; ++c) ra[c] = *(const b16x8*)&Hbuf[(size_t)agr[c]*FFD + sk];
    #pragma unroll
    for (int c = 0; c < 4; ++c) rb[c] = *(const b16x8*)&Be[(size_t)brow[c]*FFD + sk];
    #pragma unroll
    for (int c = 0; c < 2; ++c) *(b16x8*)&As[0][awr[c]] = ra[c];
    #pragma unroll
    for (int c = 0; c < 4; ++c) *(b16x8*)&Bs[0][bwr[c]] = rb[c];
    __syncthreads();

    int cur = 0;
    for (int t = 0; t < 32; ++t) {
        if (t < 31) {
            int kk = (t + 1) * 64;
            #pragma unroll
            for (int c = 0; c < 2; ++c) ra[c] = *(const b16x8*)&Hbuf[(size_t)agr[c]*FFD + kk + sk];
            #pragma unroll
            for (int c = 0; c < 4; ++c) rb[c] = *(const b16x8*)&Be[(size_t)brow[c]*FFD + kk + sk];
        }
        #pragma unroll
        for (int k2 = 0; k2 < 64; k2 += 32) {
            b16x8 af[2], bf[4];
            #pragma unroll
            for (int m = 0; m < 2; ++m)
                af[m] = *(const b16x8*)&As[cur][(am + m*16 + frow)*64 + ((k2 + fk) ^ rx)];
            #pragma unroll
            for (int n = 0; n < 4; ++n)
                bf[n] = *(const b16x8*)&Bs[cur][(bn + n*16 + frow)*64 + ((k2 + fk) ^ rx)];
            #pragma unroll
            for (int m = 0; m < 2; ++m)
                #pragma unroll
                for (int n = 0; n < 4; ++n)
                    acc[m][n] = __builtin_amdgcn_mfma_f32_16x16x32_bf16(af[m], bf[n], acc[m][n], 0, 0, 0);
        }
        __syncthreads();
        if (t < 31) {
            #pragma unroll
            for (int c = 0; c < 2; ++c) *(b16x8*)&As[cur ^ 1][awr[c]] = ra[c];
            #pragma unroll
            for (int c = 0; c < 4; ++c) *(b16x8*)&Bs[cur ^ 1][bwr[c]] = rb[c];
        }
        __syncthreads();
        cur ^= 1;
    }

    int crow = (lane >> 4) * 4;
    #pragma unroll
    for (int m = 0; m < 2; ++m) {
        #pragma unroll
        for (int i = 0; i < 4; ++i) {
            int r = mt*64 + am + m*16 + crow + i;
            if (r < ce) {
                float g = lgate[e * TT + r];
                size_t prow = (size_t)(s0 + r) * DD;
                #pragma unroll
                for (int n = 0; n < 4; ++n) {
                    int col = nt*128 + bn + n*16 + frow;
                    P[prow + col] = g * (acc[m][n][i] + b2[e * DD + col]);
                }
            }
        }
    }
}

// ---------------- Combine: out[t,d] = P[p0,d] + P[p1,d] --------------------
__global__ void moe_combine(const int* __restrict__ pair0, const int* __restrict__ pair1,
                            const int* __restrict__ seg, const float* __restrict__ P,
                            float* __restrict__ out)
{
    int idx = blockIdx.x * 256 + threadIdx.x;
    int hw   = idx & 1023;
    int rest = idx >> 10;
    int d = rest & 511;
    int b = rest >> 9;
    int t = b * 1024 + hw;
    int a0 = pair0[t], a1 = pair1[t];
    int p0 = seg[a0 >> 16] + (a0 & 0xFFFF);
    int p1 = seg[a1 >> 16] + (a1 & 0xFFFF);
    out[idx] = P[(size_t)p0 * DD + d] + P[(size_t)p1 * DD + d];
}

// ---------------- Launch ---------------------------------------------------
extern "C" void kernel_launch(void* const* d_in, const int* in_sizes, int n_in,
                              void* d_out, int out_size, void* d_ws, size_t ws_size,
                              hipStream_t stream)
{
    const float* x    = (const float*)d_in[0];
    const float* Wg   = (const float*)d_in[1];
    const float* bg   = (const float*)d_in[2];
    const float* Wn   = (const float*)d_in[3];
    const float* bn   = (const float*)d_in[4];
    const float* W1   = (const float*)d_in[5];
    const float* b1   = (const float*)d_in[6];
    const float* W2   = (const float*)d_in[7];
    const float* b2   = (const float*)d_in[8];
    const float* neps = (const float*)d_in[9];

    char* ws = (char*)d_ws;
    int*   cnt   = (int*)(ws + 0);                       // 32 B
    int*   seg   = (int*)(ws + 256);                     // 36 B
    int*   pair0 = (int*)(ws + 512);                     // 8 KB
    int*   pair1 = (int*)(ws + 8704);                    // 8 KB
    int*   ltok  = (int*)(ws + 32768);                   // 64 KB
    float* lgate = (float*)(ws + 98304);                 // 64 KB
    float* part  = (float*)(ws + 163840);                // 1 MB [8][2048][16] f32
    unsigned short* xb   = (unsigned short*)(ws + 1212416);   // 2 MB  [2048][512] bf16
    unsigned short* Hbuf = (unsigned short*)(ws + 3309568);   // 16 MB [4096][2048] bf16
    unsigned short* W1t  = (unsigned short*)(ws + 20086784);  // 16 MB [E][2048][512] bf16
    unsigned short* W2t  = (unsigned short*)(ws + 36864000);  // 16 MB [E][512][2048] bf16
    float*          P    = (float*)(ws + 20086784);           // 8 MB, aliases W1t (dead after gemm1)

    hipMemsetAsync(cnt, 0, 32, stream);
    moe_transpose<<<dim3(256, 8, 3), 256, 0, stream>>>(W1, W2, x, W1t, W2t, xb);
    moe_router_part<<<dim3(TT / 64, 8), 256, 0, stream>>>(x, Wg, Wn, part);
    moe_router_topk<<<TT / 256, 256, 0, stream>>>(part, bg, bn, neps,
                                                  cnt, pair0, pair1, ltok, lgate);
    moe_prefix<<<1, 64, 0, stream>>>(cnt, seg);
    moe_gemm1<<<dim3(EE, 32, 16), 256, 0, stream>>>(xb, W1t, b1, cnt, seg, ltok, Hbuf);
    moe_gemm2<<<dim3(EE, 32, 4), 256, 0, stream>>>(Hbuf, W2t, b2, cnt, seg, lgate, P);
    moe_combine<<<(2 * DD * HWH) / 256, 256, 0, stream>>>(pair0, pair1, seg, P, (float*)d_out);
}

// Round 4
// 106.326 us; speedup vs baseline: 1.8485x; 1.1728x over previous
//
#include <hip/hip_runtime.h>
#include <hip/hip_bf16.h>
#include <math.h>

// Problem constants
#define DD  512
#define EE  8
#define FFD 2048
#define TT  2048
#define HWH 1024

typedef __bf16 b16x8 __attribute__((ext_vector_type(8)));
typedef float  f32x4 __attribute__((ext_vector_type(4)));

__device__ __forceinline__ unsigned short f2bf(float f) {
    unsigned u = __builtin_bit_cast(unsigned, f);
    u = (u + 0x7FFFu + ((u >> 16) & 1u)) >> 16;   // RNE
    return (unsigned short)u;
}

// async global->LDS, 16B per lane; LDS dest is wave-uniform base + lane*16
__device__ __forceinline__ void gload16(const void* g, void* l) {
    __builtin_amdgcn_global_load_lds(
        (const __attribute__((address_space(1))) void*)g,
        (__attribute__((address_space(3))) void*)l, 16, 0, 0);
}

// ---------- transpose/convert: f32 [R][C] -> bf16 [C][R] -------------------
__global__ __launch_bounds__(256) void moe_transpose(
    const float* __restrict__ W1, const float* __restrict__ W2,
    const float* __restrict__ x,
    unsigned short* __restrict__ W1t, unsigned short* __restrict__ W2t,
    unsigned short* __restrict__ xb)
{
    int which = blockIdx.z, e = blockIdx.y;
    const float* in; unsigned short* out; int R, C;
    if (which == 0)      { R = DD;  C = FFD; in = W1 + (size_t)e*DD*FFD; out = W1t + (size_t)e*FFD*DD; }
    else if (which == 1) { R = FFD; C = DD;  in = W2 + (size_t)e*FFD*DD; out = W2t + (size_t)e*DD*FFD; }
    else { if (e >= 2) return; R = DD; C = HWH; in = x + (size_t)e*DD*HWH; out = xb + (size_t)e*HWH*DD; }
    int tilesC = C >> 6;
    if ((int)blockIdx.x >= (R >> 6) * tilesC) return;
    int tr = (blockIdx.x / tilesC) << 6, tc = (blockIdx.x % tilesC) << 6;
    __shared__ float ld[64][65];
    int ty = threadIdx.x >> 4, tx = threadIdx.x & 15;
    #pragma unroll
    for (int i = 0; i < 4; ++i) {
        const float4 v = *(const float4*)&in[(size_t)(tr + ty + i*16)*C + tc + tx*4];
        ld[ty + i*16][tx*4+0] = v.x; ld[ty + i*16][tx*4+1] = v.y;
        ld[ty + i*16][tx*4+2] = v.z; ld[ty + i*16][tx*4+3] = v.w;
    }
    __syncthreads();
    #pragma unroll
    for (int i = 0; i < 4; ++i) {
        int c = ty + i*16;
        unsigned o0 = f2bf(ld[tx*4+0][c]) | ((unsigned)f2bf(ld[tx*4+1][c]) << 16);
        unsigned o1 = f2bf(ld[tx*4+2][c]) | ((unsigned)f2bf(ld[tx*4+3][c]) << 16);
        *(uint2*)&out[(size_t)(tc + c)*R + tr + tx*4] = make_uint2(o0, o1);
    }
}

// ---------------- Router stage A: partial GEMV over a 64-d slice -----------
// part layout: [8 dchunk][2048 token][16 (L0..7,N0..7)] f32  (1 MB)
__global__ __launch_bounds__(256) void moe_router_part(
    const float* __restrict__ x, const float* __restrict__ Wg,
    const float* __restrict__ Wn, float* __restrict__ part)
{
    int u = threadIdx.x & 63;
    int q = threadIdx.x >> 6;
    int tt = blockIdx.x, dc = blockIdx.y;
    int t = tt * 64 + u;
    int b = t >> 10, hw = t & 1023;
    const float* xp = x + (size_t)b * DD * HWH + hw;
    int d0 = dc * 64 + q * 16;
    float accL[EE], accN[EE];
    #pragma unroll
    for (int e = 0; e < EE; ++e) { accL[e] = 0.f; accN[e] = 0.f; }
    #pragma unroll
    for (int i = 0; i < 16; ++i) {
        int d = d0 + i;
        float tv = xp[(size_t)d * HWH];
        #pragma unroll
        for (int e = 0; e < EE; ++e) {
            accL[e] = fmaf(tv, Wg[d * EE + e], accL[e]);
            accN[e] = fmaf(tv, Wn[d * EE + e], accN[e]);
        }
    }
    __shared__ float s[4][64][16];
    #pragma unroll
    for (int e = 0; e < EE; ++e) { s[q][u][e] = accL[e]; s[q][u][e + 8] = accN[e]; }
    __syncthreads();
    int idx = threadIdx.x * 4;
    int ot = idx >> 4, oc = idx & 15;
    float4 v;
    v.x = s[0][ot][oc+0] + s[1][ot][oc+0] + s[2][ot][oc+0] + s[3][ot][oc+0];
    v.y = s[0][ot][oc+1] + s[1][ot][oc+1] + s[2][ot][oc+1] + s[3][ot][oc+1];
    v.z = s[0][ot][oc+2] + s[1][ot][oc+2] + s[2][ot][oc+2] + s[3][ot][oc+2];
    v.w = s[0][ot][oc+3] + s[1][ot][oc+3] + s[2][ot][oc+3] + s[3][ot][oc+3];
    *(float4*)&part[((size_t)dc * TT + tt * 64 + ot) * 16 + oc] = v;
}

// ---------------- Router stage B: reduce + noisy top-2 + gates -------------
__global__ __launch_bounds__(256) void moe_router_topk(
    const float* __restrict__ part,
    const float* __restrict__ bg, const float* __restrict__ bn,
    const float* __restrict__ neps,
    int* __restrict__ cnt, int* __restrict__ pair0, int* __restrict__ pair1,
    int* __restrict__ ltok, float* __restrict__ lgate)
{
    int t = blockIdx.x * 256 + threadIdx.x;
    float L[EE], N[EE];
    #pragma unroll
    for (int e = 0; e < EE; ++e) { L[e] = bg[e]; N[e] = bn[e]; }
    #pragma unroll
    for (int dc = 0; dc < 8; ++dc) {
        const float* p = &part[((size_t)dc * TT + t) * 16];
        float4 a0 = *(const float4*)&p[0];
        float4 a1 = *(const float4*)&p[4];
        float4 a2 = *(const float4*)&p[8];
        float4 a3 = *(const float4*)&p[12];
        L[0] += a0.x; L[1] += a0.y; L[2] += a0.z; L[3] += a0.w;
        L[4] += a1.x; L[5] += a1.y; L[6] += a1.z; L[7] += a1.w;
        N[0] += a2.x; N[1] += a2.y; N[2] += a2.z; N[3] += a2.w;
        N[4] += a3.x; N[5] += a3.y; N[6] += a3.z; N[7] += a3.w;
    }
    float noisy[EE];
    #pragma unroll
    for (int e = 0; e < EE; ++e) {
        float sp = fmaxf(N[e], 0.f) + log1pf(expf(-fabsf(N[e])));   // softplus
        noisy[e] = L[e] + neps[t * EE + e] * sp;
    }
    int e0 = 0; float v0 = noisy[0];
    #pragma unroll
    for (int e = 1; e < EE; ++e) if (noisy[e] > v0) { v0 = noisy[e]; e0 = e; }
    int e1 = (e0 == 0) ? 1 : 0; float v1 = noisy[e1];
    #pragma unroll
    for (int e = 0; e < EE; ++e)
        if (e != e0 && e != e1 && noisy[e] > v1) { v1 = noisy[e]; e1 = e; }
    float ex  = expf(v1 - v0);
    float inv = 1.f / (1.f + ex);
    float g0 = inv, g1 = ex * inv;
    int p0 = atomicAdd(&cnt[e0], 1);
    int p1 = atomicAdd(&cnt[e1], 1);
    ltok[e0 * TT + p0] = t; lgate[e0 * TT + p0] = g0;
    ltok[e1 * TT + p1] = t; lgate[e1 * TT + p1] = g1;
    pair0[t] = (e0 << 16) | p0;
    pair1[t] = (e1 << 16) | p1;
}

// ---------------- Prefix sum over 8 expert counts --------------------------
__global__ void moe_prefix(const int* __restrict__ cnt, int* __restrict__ seg)
{
    if (threadIdx.x == 0) {
        int s = 0;
        for (int e = 0; e < EE; ++e) { seg[e] = s; s += cnt[e]; }
        seg[EE] = s;
    }
}

// ---------------- GEMM1: H = relu(tok @ W1t^T + b1)  (64x128 tile, BK=64) --
// global_load_lds staging: LDS linear, XOR swizzle applied on GLOBAL source.
__global__ __launch_bounds__(256, 3) void moe_gemm1(
    const unsigned short* __restrict__ xb, const unsigned short* __restrict__ W1t,
    const float* __restrict__ b1, const int* __restrict__ cnt,
    const int* __restrict__ seg, const int* __restrict__ ltok,
    unsigned short* __restrict__ Hbuf)
{
    int e = blockIdx.x, mt = blockIdx.y, nt = blockIdx.z;
    int ce = cnt[e];
    if (mt * 64 >= ce) return;
    int s0 = seg[e];
    const unsigned short* Be = W1t + (size_t)e * FFD * DD;   // [FF][D] bf16
    __shared__ unsigned short As[2][64 * 64];
    __shared__ unsigned short Bs[2][128 * 64];
    int tid = threadIdx.x, lane = tid & 63, wv = tid >> 6;

    int srow = lane >> 3, schunk = lane & 7;
    int srcoff = ((schunk ^ srow) << 3);       // swizzled source chunk (elems)

    // A source rows (token-indirect), per lane
    size_t aoff[2]; int ards[2];
    #pragma unroll
    for (int c = 0; c < 2; ++c) {
        int r0 = (c*4 + wv)*8;
        int ri = mt*64 + r0 + srow;
        int tok = ltok[e * TT + (ri < ce ? ri : 0)];
        aoff[c] = (size_t)tok * DD + srcoff;
        ards[c] = r0 * 64;                     // wave-uniform LDS base (elems)
    }
    size_t boff[4]; int brds[4];
    #pragma unroll
    for (int c = 0; c < 4; ++c) {
        int r0 = (c*4 + wv)*8;
        boff[c] = (size_t)(nt*128 + r0 + srow) * DD + srcoff;
        brds[c] = r0 * 64;
    }

    int frow = lane & 15, fk = (lane >> 4) * 8;
    int am = (wv >> 1) * 32, bnn = (wv & 1) * 64;
    int rx = (frow & 7) << 3;

    f32x4 acc[2][4];
    f32x4 zero = {0.f, 0.f, 0.f, 0.f};
    #pragma unroll
    for (int m = 0; m < 2; ++m)
        #pragma unroll
        for (int n = 0; n < 4; ++n) acc[m][n] = zero;

    // prologue: stage k-tile 0 into buf 0
    #pragma unroll
    for (int c = 0; c < 2; ++c) gload16(&xb[aoff[c]], &As[0][ards[c]]);
    #pragma unroll
    for (int c = 0; c < 4; ++c) gload16(&Be[boff[c]], &Bs[0][brds[c]]);
    __syncthreads();

    int cur = 0;
    for (int t = 0; t < 8; ++t) {
        if (t < 7) {
            int kk = (t + 1) * 64;
            #pragma unroll
            for (int c = 0; c < 2; ++c) gload16(&xb[aoff[c] + kk], &As[cur^1][ards[c]]);
            #pragma unroll
            for (int c = 0; c < 4; ++c) gload16(&Be[boff[c] + kk], &Bs[cur^1][brds[c]]);
        }
        #pragma unroll
        for (int k2 = 0; k2 < 64; k2 += 32) {
            b16x8 af[2], bf[4];
            #pragma unroll
            for (int m = 0; m < 2; ++m)
                af[m] = *(const b16x8*)&As[cur][(am + m*16 + frow)*64 + ((k2 + fk) ^ rx)];
            #pragma unroll
            for (int n = 0; n < 4; ++n)
                bf[n] = *(const b16x8*)&Bs[cur][(bnn + n*16 + frow)*64 + ((k2 + fk) ^ rx)];
            #pragma unroll
            for (int m = 0; m < 2; ++m)
                #pragma unroll
                for (int n = 0; n < 4; ++n)
                    acc[m][n] = __builtin_amdgcn_mfma_f32_16x16x32_bf16(af[m], bf[n], acc[m][n], 0, 0, 0);
        }
        __syncthreads();     // drains vmcnt (loads into buf^1) + readers done
        cur ^= 1;
    }

    int crow = (lane >> 4) * 4;
    #pragma unroll
    for (int m = 0; m < 2; ++m) {
        #pragma unroll
        for (int i = 0; i < 4; ++i) {
            int r = mt*64 + am + m*16 + crow + i;
            if (r < ce) {
                size_t hrow = (size_t)(s0 + r) * FFD;
                #pragma unroll
                for (int n = 0; n < 4; ++n) {
                    int col = nt*128 + bnn + n*16 + frow;
                    float v = acc[m][n][i] + b1[e * FFD + col];
                    Hbuf[hrow + col] = f2bf(fmaxf(v, 0.f));
                }
            }
        }
    }
}

// ---------------- GEMM2: P4[s] = H @ W2t^T  (split-K x4, 64x128 tile) ------
// z = split*4 + nt ; each split handles K-range [split*512, split*512+512)
__global__ __launch_bounds__(256, 3) void moe_gemm2(
    const unsigned short* __restrict__ Hbuf, const unsigned short* __restrict__ W2t,
    const int* __restrict__ cnt, const int* __restrict__ seg,
    float* __restrict__ P4)
{
    int e = blockIdx.x, mt = blockIdx.y;
    int split = blockIdx.z >> 2, nt = blockIdx.z & 3;
    int ce = cnt[e];
    if (mt * 64 >= ce) return;
    int s0 = seg[e];
    int kbase = split * 512;
    const unsigned short* Be = W2t + (size_t)e * DD * FFD;   // [D][FF] bf16
    __shared__ unsigned short As[2][64 * 64];
    __shared__ unsigned short Bs[2][128 * 64];
    int tid = threadIdx.x, lane = tid & 63, wv = tid >> 6;

    int srow = lane >> 3, schunk = lane & 7;
    int srcoff = ((schunk ^ srow) << 3);

    size_t aoff[2]; int ards[2];
    #pragma unroll
    for (int c = 0; c < 2; ++c) {
        int r0 = (c*4 + wv)*8;
        int g = s0 + mt*64 + r0 + srow; if (g > 4095) g = 4095;
        aoff[c] = (size_t)g * FFD + kbase + srcoff;
        ards[c] = r0 * 64;
    }
    size_t boff[4]; int brds[4];
    #pragma unroll
    for (int c = 0; c < 4; ++c) {
        int r0 = (c*4 + wv)*8;
        boff[c] = (size_t)(nt*128 + r0 + srow) * FFD + kbase + srcoff;
        brds[c] = r0 * 64;
    }

    int frow = lane & 15, fk = (lane >> 4) * 8;
    int am = (wv >> 1) * 32, bnn = (wv & 1) * 64;
    int rx = (frow & 7) << 3;

    f32x4 acc[2][4];
    f32x4 zero = {0.f, 0.f, 0.f, 0.f};
    #pragma unroll
    for (int m = 0; m < 2; ++m)
        #pragma unroll
        for (int n = 0; n < 4; ++n) acc[m][n] = zero;

    #pragma unroll
    for (int c = 0; c < 2; ++c) gload16(&Hbuf[aoff[c]], &As[0][ards[c]]);
    #pragma unroll
    for (int c = 0; c < 4; ++c) gload16(&Be[boff[c]], &Bs[0][brds[c]]);
    __syncthreads();

    int cur = 0;
    for (int t = 0; t < 8; ++t) {
        if (t < 7) {
            int kk = (t + 1) * 64;
            #pragma unroll
            for (int c = 0; c < 2; ++c) gload16(&Hbuf[aoff[c] + kk], &As[cur^1][ards[c]]);
            #pragma unroll
            for (int c = 0; c < 4; ++c) gload16(&Be[boff[c] + kk], &Bs[cur^1][brds[c]]);
        }
        #pragma unroll
        for (int k2 = 0; k2 < 64; k2 += 32) {
            b16x8 af[2], bf[4];
            #pragma unroll
            for (int m = 0; m < 2; ++m)
                af[m] = *(const b16x8*)&As[cur][(am + m*16 + frow)*64 + ((k2 + fk) ^ rx)];
            #pragma unroll
            for (int n = 0; n < 4; ++n)
                bf[n] = *(const b16x8*)&Bs[cur][(bnn + n*16 + frow)*64 + ((k2 + fk) ^ rx)];
            #pragma unroll
            for (int m = 0; m < 2; ++m)
                #pragma unroll
                for (int n = 0; n < 4; ++n)
                    acc[m][n] = __builtin_amdgcn_mfma_f32_16x16x32_bf16(af[m], bf[n], acc[m][n], 0, 0, 0);
        }
        __syncthreads();
        cur ^= 1;
    }

    int crow = (lane >> 4) * 4;
    float* Pw = P4 + (size_t)split * 4096 * DD;
    #pragma unroll
    for (int m = 0; m < 2; ++m) {
        #pragma unroll
        for (int i = 0; i < 4; ++i) {
            int r = mt*64 + am + m*16 + crow + i;
            if (r < ce) {
                size_t prow = (size_t)(s0 + r) * DD;
                #pragma unroll
                for (int n = 0; n < 4; ++n) {
                    int col = nt*128 + bnn + n*16 + frow;
                    Pw[prow + col] = acc[m][n][i];
                }
            }
        }
    }
}

// ------ Combine: out[t,d] = sum_pairs gate*(sum_splits P4 + b2[e])  --------
// 32-token x 64-d tiles; coalesced reads, LDS transpose, coalesced writes.
__global__ __launch_bounds__(256) void moe_combine(
    const int* __restrict__ pair0, const int* __restrict__ pair1,
    const int* __restrict__ seg, const float* __restrict__ lgate,
    const float* __restrict__ b2, const float* __restrict__ P4,
    float* __restrict__ out)
{
    __shared__ float tile[32][68];
    int tid = threadIdx.x;
    int ti = blockIdx.x, dc = blockIdx.y;
    // ---- read/reduce phase: ty = token(0..31), tx = d-octet(0..7)
    int ty = tid >> 3, tx = tid & 7;
    int t = ti * 32 + ty;
    int a0 = pair0[t], a1 = pair1[t];
    int e0 = a0 >> 16, sl0 = a0 & 0xFFFF;
    int e1 = a1 >> 16, sl1 = a1 & 0xFFFF;
    int p0 = seg[e0] + sl0, p1 = seg[e1] + sl1;
    float g0 = lgate[e0 * TT + sl0], g1 = lgate[e1 * TT + sl1];
    int d0 = dc * 64 + tx * 8;
    f32x4 s0v[2] = {{0,0,0,0},{0,0,0,0}}, s1v[2] = {{0,0,0,0},{0,0,0,0}};
    #pragma unroll
    for (int s = 0; s < 4; ++s) {
        const f32x4* r0p = (const f32x4*)(P4 + ((size_t)s * 4096 + p0) * DD + d0);
        const f32x4* r1p = (const f32x4*)(P4 + ((size_t)s * 4096 + p1) * DD + d0);
        s0v[0] += r0p[0]; s0v[1] += r0p[1];
        s1v[0] += r1p[0]; s1v[1] += r1p[1];
    }
    const f32x4* b0p = (const f32x4*)(b2 + e0 * DD + d0);
    const f32x4* b1p = (const f32x4*)(b2 + e1 * DD + d0);
    #pragma unroll
    for (int q = 0; q < 2; ++q) {
        f32x4 v = g0 * (s0v[q] + b0p[q]) + g1 * (s1v[q] + b1p[q]);
        *(f32x4*)&tile[ty][tx*8 + q*4] = v;
    }
    __syncthreads();
    // ---- write phase: dy = d(0..63), hx = hw-octet(0..3)
    int dy = tid >> 2, hx = tid & 3;
    int b = (ti * 32) >> 10, hw0 = (ti * 32) & 1023;
    size_t obase = ((size_t)(b * DD + dc * 64 + dy)) * HWH + hw0;
    #pragma unroll
    for (int q = 0; q < 2; ++q) {
        int j = hx * 8 + q * 4;
        float4 w;
        w.x = tile[j + 0][dy];
        w.y = tile[j + 1][dy];
        w.z = tile[j + 2][dy];
        w.w = tile[j + 3][dy];
        *(float4*)&out[obase + j] = w;
    }
}

// ---------------- Launch ---------------------------------------------------
extern "C" void kernel_launch(void* const* d_in, const int* in_sizes, int n_in,
                              void* d_out, int out_size, void* d_ws, size_t ws_size,
                              hipStream_t stream)
{
    const float* x    = (const float*)d_in[0];
    const float* Wg   = (const float*)d_in[1];
    const float* bg   = (const float*)d_in[2];
    const float* Wn   = (const float*)d_in[3];
    const float* bn   = (const float*)d_in[4];
    const float* W1   = (const float*)d_in[5];
    const float* b1   = (const float*)d_in[6];
    const float* W2   = (const float*)d_in[7];
    const float* b2   = (const float*)d_in[8];
    const float* neps = (const float*)d_in[9];

    char* ws = (char*)d_ws;
    int*   cnt   = (int*)(ws + 0);                       // 32 B
    int*   seg   = (int*)(ws + 256);                     // 36 B
    int*   pair0 = (int*)(ws + 512);                     // 8 KB
    int*   pair1 = (int*)(ws + 8704);                    // 8 KB
    int*   ltok  = (int*)(ws + 32768);                   // 64 KB
    float* lgate = (float*)(ws + 98304);                 // 64 KB
    float* part  = (float*)(ws + 163840);                // 1 MB [8][2048][16] f32
    unsigned short* xb   = (unsigned short*)(ws + 1212416);   // 2 MB  [2048][512] bf16
    unsigned short* Hbuf = (unsigned short*)(ws + 3309568);   // 16 MB [4096][2048] bf16
    unsigned short* W1t  = (unsigned short*)(ws + 20086784);  // 16 MB [E][2048][512] bf16
    unsigned short* W2t  = (unsigned short*)(ws + 36864000);  // 16 MB [E][512][2048] bf16
    float*          P4   = (float*)(ws + 53641216);           // 32 MB [4][4096][512] f32
    // ws high-water ~87 MB (ws_size = 256 MB per fillBuffer observation)

    hipMemsetAsync(cnt, 0, 32, stream);
    moe_transpose<<<dim3(256, 8, 3), 256, 0, stream>>>(W1, W2, x, W1t, W2t, xb);
    moe_router_part<<<dim3(TT / 64, 8), 256, 0, stream>>>(x, Wg, Wn, part);
    moe_router_topk<<<TT / 256, 256, 0, stream>>>(part, bg, bn, neps,
                                                  cnt, pair0, pair1, ltok, lgate);
    moe_prefix<<<1, 64, 0, stream>>>(cnt, seg);
    moe_gemm1<<<dim3(EE, 32, 16), 256, 0, stream>>>(xb, W1t, b1, cnt, seg, ltok, Hbuf);
    moe_gemm2<<<dim3(EE, 32, 16), 256, 0, stream>>>(Hbuf, W2t, cnt, seg, P4);
    moe_combine<<<dim3(TT / 32, 8), 256, 0, stream>>>(pair0, pair1, seg, lgate, b2, P4, (float*)d_out);
}